// Round 2
// baseline (1620.433 us; speedup 1.0000x reference)
//
#include <hip/hip_runtime.h>

#define N_NODES 20000
#define N_EDGES 320000
#define F_DIM   128
#define H_DIM   256
#define M_ROWS  4096
#define NQ      2048
#define NIT     44

// ---------------- helpers ----------------

__device__ __forceinline__ float wred(float v) {
#pragma unroll
  for (int m = 32; m > 0; m >>= 1) v += __shfl_xor(v, m, 64);
  return v;
}

__device__ __forceinline__ float bred256(float v, float* lds) {
  v = wred(v);
  int w = threadIdx.x >> 6;
  if ((threadIdx.x & 63) == 0) lds[w] = v;
  __syncthreads();
  float tot = lds[0] + lds[1] + lds[2] + lds[3];
  __syncthreads();
  return tot;
}

__device__ __forceinline__ unsigned short f2bf(float f) {
  unsigned u = __float_as_uint(f);
  unsigned r = u + 0x7fffu + ((u >> 16) & 1u);
  return (unsigned short)(r >> 16);
}
__device__ __forceinline__ float bflo(unsigned u) { return __uint_as_float(u << 16); }
__device__ __forceinline__ float bfhi(unsigned u) { return __uint_as_float(u & 0xffff0000u); }

// ---------------- CSR build ----------------

__global__ __launch_bounds__(256) void k_deg(const int* __restrict__ ei, int* __restrict__ deg) {
  int e = blockIdx.x * 256 + threadIdx.x;
  if (e < N_EDGES) atomicAdd(&deg[ei[e]], 1);
}

__global__ __launch_bounds__(256) void k_dinv(const int* __restrict__ deg, float* __restrict__ dinv) {
  int i = blockIdx.x * 256 + threadIdx.x;
  if (i < N_NODES) {
    int d = deg[i];
    dinv[i] = d > 0 ? rsqrtf((float)d) : 0.f;
  }
}

__global__ __launch_bounds__(1024) void k_scan(const int* __restrict__ deg, int* __restrict__ rowstart) {
  __shared__ int part[1024];
  int t = threadIdx.x;
  const int chunk = (N_NODES + 1023) / 1024;  // 20
  int lo = t * chunk;
  int hi = lo + chunk; if (hi > N_NODES) hi = N_NODES;
  int s = 0;
  for (int i = lo; i < hi; ++i) s += deg[i];
  part[t] = s;
  __syncthreads();
  for (int off = 1; off < 1024; off <<= 1) {
    int v = part[t];
    int add = (t >= off) ? part[t - off] : 0;
    __syncthreads();
    part[t] = v + add;
    __syncthreads();
  }
  int base = (t > 0) ? part[t - 1] : 0;
  for (int i = lo; i < hi; ++i) { rowstart[i] = base; base += deg[i]; }
  if (t == 0) rowstart[N_NODES] = part[1023];
}

__global__ __launch_bounds__(256) void k_scatter(const int* __restrict__ ei,
    const int* __restrict__ rowstart, int* __restrict__ cursor,
    const float* __restrict__ dinv, int* __restrict__ cols, float* __restrict__ wvals) {
  int e = blockIdx.x * 256 + threadIdx.x;
  if (e >= N_EDGES) return;
  int r = ei[e];
  int c = ei[N_EDGES + e];
  int pos = rowstart[r] + atomicAdd(&cursor[r], 1);
  cols[pos] = c;
  wvals[pos] = -dinv[r] * dinv[c];
}

// ---------------- GNN layer 1 ----------------

__global__ __launch_bounds__(256) void k_msg1(const float* __restrict__ x,
    const int* __restrict__ rowstart, const int* __restrict__ cols,
    const float* __restrict__ wvals, float* __restrict__ msg) {
  int wid = (blockIdx.x * 256 + threadIdx.x) >> 6;
  int lane = threadIdx.x & 63;
  if (wid >= N_NODES) return;
  int s0 = rowstart[wid], s1 = rowstart[wid + 1];
  const float2* x2 = (const float2*)x;
  float2 acc = make_float2(0.f, 0.f);
  for (int e = s0; e < s1; ++e) {
    int c = cols[e];
    float w = wvals[e];
    float2 xv = x2[(size_t)c * 64 + lane];
    acc.x += w * xv.x;
    acc.y += w * xv.y;
  }
  ((float2*)msg)[(size_t)wid * 64 + lane] = acc;
}

// h = relu(x@W10 + msg@W11 + b1); then t += h.W20, s += h.W21 fused (no h store)
__global__ __launch_bounds__(256) void k_gemm1(const float* __restrict__ x,
    const float* __restrict__ msg, const float* __restrict__ W10,
    const float* __restrict__ W11, const float* __restrict__ b1,
    const float* __restrict__ W20, const float* __restrict__ W21,
    float* __restrict__ t, float* __restrict__ s) {
  __shared__ float As[32][68];
  __shared__ float Bs[32][68];
  const int row0 = blockIdx.x * 64;
  const int col0 = blockIdx.y * 64;
  const int tid = threadIdx.x;
  const int tx = tid & 15, ty = tid >> 4;
  float acc[4][4] = {};
  for (int pass = 0; pass < 2; ++pass) {
    const float* Am = pass ? msg : x;
    const float* Bm = pass ? W11 : W10;
    for (int k0 = 0; k0 < F_DIM; k0 += 32) {
#pragma unroll
      for (int e = 0; e < 8; ++e) {
        int idx = tid + e * 256;
        int i = idx >> 5, kk = idx & 31;
        int gr = row0 + i;
        As[kk][i] = (gr < N_NODES) ? Am[(size_t)gr * F_DIM + k0 + kk] : 0.f;
      }
#pragma unroll
      for (int e = 0; e < 8; ++e) {
        int idx = tid + e * 256;
        int kk = idx >> 6, j = idx & 63;
        Bs[kk][j] = Bm[(size_t)(k0 + kk) * H_DIM + col0 + j];
      }
      __syncthreads();
#pragma unroll
      for (int kk = 0; kk < 32; ++kk) {
        float4 a = *(const float4*)&As[kk][ty * 4];
        float4 b = *(const float4*)&Bs[kk][tx * 4];
        float av[4] = {a.x, a.y, a.z, a.w};
        float bv[4] = {b.x, b.y, b.z, b.w};
#pragma unroll
        for (int ii = 0; ii < 4; ++ii)
#pragma unroll
          for (int jj = 0; jj < 4; ++jj) acc[ii][jj] += av[ii] * bv[jj];
      }
      __syncthreads();
    }
  }
  // epilogue: relu + project onto W20/W21, reduce over this block's 64 cols
#pragma unroll
  for (int ii = 0; ii < 4; ++ii) {
    int gr = row0 + ty * 4 + ii;
    float tp = 0.f, sp = 0.f;
#pragma unroll
    for (int jj = 0; jj < 4; ++jj) {
      int c = col0 + tx * 4 + jj;
      float val = acc[ii][jj] + b1[c];
      val = val > 0.f ? val : 0.f;
      tp += val * W20[c];
      sp += val * W21[c];
    }
#pragma unroll
    for (int m = 1; m < 16; m <<= 1) {
      tp += __shfl_xor(tp, m, 64);
      sp += __shfl_xor(sp, m, 64);
    }
    if (tx == 0 && gr < N_NODES) {
      atomicAdd(&t[gr], tp);
      atomicAdd(&s[gr], sp);
    }
  }
}

// ---------------- GNN layer 2 scalar gather ----------------

__global__ __launch_bounds__(256) void k_h2(const float* __restrict__ t,
    const float* __restrict__ s, const int* __restrict__ rowstart,
    const int* __restrict__ cols, const float* __restrict__ wvals,
    const float* __restrict__ lamb, const float* __restrict__ b2, float* __restrict__ h2) {
  int i = blockIdx.x * 256 + threadIdx.x;
  if (i >= N_NODES) return;
  float m = 0.f;
  int s0 = rowstart[i], s1 = rowstart[i + 1];
  for (int e = s0; e < s1; ++e) m += wvals[e] * s[cols[e]];
  float val = t[i] + m + b2[0];
  val = val > 0.f ? val : 0.f;
  h2[i] = lamb[0] * val;
}

// ---------------- QP setup: bf16 convert A + b^T A partials ----------------
// grid (4, 32): thread -> col pair (2*jp, 2*jp+1), 128-row chunk by.
__global__ __launch_bounds__(256) void k_prep(const float* __restrict__ A,
    const float* __restrict__ b, unsigned* __restrict__ Au, float* __restrict__ btA_parts) {
  int jp = blockIdx.x * 256 + threadIdx.x;   // 0..1023
  int k0 = blockIdx.y * 128;
  const float2* A2 = (const float2*)A;
  float acc0 = 0.f, acc1 = 0.f;
#pragma unroll 4
  for (int kk = 0; kk < 128; ++kk) {
    int k = k0 + kk;
    float2 a = A2[(size_t)k * 1024 + jp];
    float bk = b[k];
    acc0 += a.x * bk;
    acc1 += a.y * bk;
    unsigned lo = f2bf(a.x), hi = f2bf(a.y);
    Au[(size_t)k * 1024 + jp] = lo | (hi << 16);
  }
  ((float2*)(btA_parts + (size_t)blockIdx.y * NQ))[jp] = make_float2(acc0, acc1);
}

// rhs/q/cg-init fused
__global__ __launch_bounds__(256) void k_qrhs(const float* __restrict__ h2,
    const int* __restrict__ feat_ids, const float* __restrict__ x_prior,
    const float* __restrict__ btA_parts, float* __restrict__ q,
    float* __restrict__ r, float* __restrict__ p0, float* __restrict__ rr_parts) {
  __shared__ float lds[4];
  int j = blockIdx.x * 256 + threadIdx.x;
  int f = feat_ids[j];
  float hf = h2[f] + 1e-5f;
  q[j] = hf;
  float bta = 0.f;
#pragma unroll
  for (int c = 0; c < 32; ++c) bta += btA_parts[(size_t)c * NQ + j];
  float rhsv = x_prior[j] * hf + bta;  // rhs = -p
  r[j] = rhsv;
  p0[j] = rhsv;
  float tot = bred256(rhsv * rhsv, lds);
  if (threadIdx.x == 0) rr_parts[blockIdx.x] = tot;
}

// ---------------- CG iteration (3 kernels) ----------------
// Kernel 1: fold p-update (beta from rr partials, p_new = r + beta*p_prev),
// write p_new, compute v = A p_new. One wave per 4 rows; grid 256x256.
__global__ __launch_bounds__(256) void k_Ap(int k, const unsigned* __restrict__ Au,
    const float* __restrict__ r, const float* __restrict__ p_prev,
    float* __restrict__ p_cur, const float* __restrict__ rr_parts,
    float* __restrict__ v) {
  int gtid = blockIdx.x * 256 + threadIdx.x;
  int wid = gtid >> 6;
  int lane = threadIdx.x & 63;

  float beta = 0.f;
  if (k > 0) {
    float rrn = 0.f, rro = 0.f;
#pragma unroll
    for (int i = 0; i < 8; ++i) {
      rrn += rr_parts[k * 8 + i];
      rro += rr_parts[(k - 1) * 8 + i];
    }
    beta = rrn / rro;
  }

  // this wave's p slice: j = c*512 + lane*8 + t
  float pn[4][8];
  const float4* r4 = (const float4*)r;
  const float4* pp4 = (const float4*)p_prev;
#pragma unroll
  for (int c = 0; c < 4; ++c) {
    int base4 = (c * 512 + lane * 8) >> 2;  // float4 index
#pragma unroll
    for (int h = 0; h < 2; ++h) {
      float4 rv = r4[base4 + h];
      float4 pv = (k > 0) ? pp4[base4 + h] : make_float4(0.f, 0.f, 0.f, 0.f);
      pn[c][h * 4 + 0] = rv.x + beta * pv.x;
      pn[c][h * 4 + 1] = rv.y + beta * pv.y;
      pn[c][h * 4 + 2] = rv.z + beta * pv.z;
      pn[c][h * 4 + 3] = rv.w + beta * pv.w;
    }
  }
  // designated threads persist p_new (k==0: p_cur already holds rhs from init)
  if (k > 0 && gtid < NQ) p_cur[gtid] = r[gtid] + beta * p_prev[gtid];

#pragma unroll
  for (int rr = 0; rr < 4; ++rr) {
    int row = wid * 4 + rr;
    const uint4* Ar = (const uint4*)(Au + (size_t)row * 1024);
    float acc = 0.f;
#pragma unroll
    for (int c = 0; c < 4; ++c) {
      uint4 a = Ar[c * 128 + lane * 2];   // wait: uint4 = 16B = 8 bf16
      // j base = c*512 + lane*8 ; uint index = (c*512+lane*8)/2 = c*256+lane*4 ; uint4 index = c*64+lane
      (void)a;
      uint4 av = ((const uint4*)(Au + (size_t)row * 1024))[c * 64 + lane];
      acc += bflo(av.x) * pn[c][0] + bfhi(av.x) * pn[c][1];
      acc += bflo(av.y) * pn[c][2] + bfhi(av.y) * pn[c][3];
      acc += bflo(av.z) * pn[c][4] + bfhi(av.z) * pn[c][5];
      acc += bflo(av.w) * pn[c][6] + bfhi(av.w) * pn[c][7];
    }
    acc = wred(acc);
    if (lane == 0) v[row] = acc;
  }
}

// Kernel 2: Qp_parts[by][j] partial A^T v over 64-row chunks; pAp partials.
// grid (4, 64); thread handles col pair.
__global__ __launch_bounds__(256) void k_ATv(const unsigned* __restrict__ Au,
    const float* __restrict__ v, const float* __restrict__ p_cur, const float* __restrict__ q,
    float* __restrict__ Qp_parts, float* __restrict__ pAp_parts) {
  __shared__ float lds[4];
  int jp = blockIdx.x * 256 + threadIdx.x;  // 0..1023
  int k0 = blockIdx.y * 64;
  float acc0 = 0.f, acc1 = 0.f;
#pragma unroll 8
  for (int kk = 0; kk < 64; ++kk) {
    int k = k0 + kk;
    unsigned a = Au[(size_t)k * 1024 + jp];
    float vk = v[k];
    acc0 += bflo(a) * vk;
    acc1 += bfhi(a) * vk;
  }
  ((float2*)(Qp_parts + (size_t)blockIdx.y * NQ))[jp] = make_float2(acc0, acc1);
  float2 p2 = ((const float2*)p_cur)[jp];
  float contrib = p2.x * acc0 + p2.y * acc1;
  if (blockIdx.y == 0) {
    float2 q2 = ((const float2*)q)[jp];
    contrib += q2.x * p2.x * p2.x + q2.y * p2.y * p2.y;
  }
  float tot = bred256(contrib, lds);
  if (threadIdx.x == 0) pAp_parts[blockIdx.y * 4 + blockIdx.x] = tot;
}

// Kernel 3: alpha, x/r update, new rr partials; final iter also writes out.
__global__ __launch_bounds__(256) void k_update(int k, const float* __restrict__ Qp_parts,
    const float* __restrict__ pAp_parts, float* __restrict__ rr_parts,
    const float* __restrict__ q, const float* __restrict__ p_cur,
    float* __restrict__ xcg, float* __restrict__ rvec, float* __restrict__ out) {
  __shared__ float lds[4];
  int tx = threadIdx.x;
  int j = blockIdx.x * 256 + tx;
  float pAp = bred256(pAp_parts[tx], lds);
  float rro = 0.f;
#pragma unroll
  for (int i = 0; i < 8; ++i) rro += rr_parts[k * 8 + i];
  float alpha = rro / pAp;
  float pj = p_cur[j];
  float Qpj = q[j] * pj;
#pragma unroll
  for (int c = 0; c < 64; ++c) Qpj += Qp_parts[(size_t)c * NQ + j];
  float xn = xcg[j] + alpha * pj;
  xcg[j] = xn;
  float rj = rvec[j] - alpha * Qpj;
  rvec[j] = rj;
  if (k == NIT - 1) out[j] = xn;
  float rrn = bred256(rj * rj, lds);
  if (tx == 0) rr_parts[(k + 1) * 8 + blockIdx.x] = rrn;
}

// ---------------- launch ----------------

extern "C" void kernel_launch(void* const* d_in, const int* in_sizes, int n_in,
                              void* d_out, int out_size, void* d_ws, size_t ws_size,
                              hipStream_t stream) {
  const float* x      = (const float*)d_in[0];
  const int*   ei     = (const int*)d_in[1];
  const float* A      = (const float*)d_in[2];
  const float* b      = (const float*)d_in[3];
  const int*   fids   = (const int*)d_in[4];
  const float* xprior = (const float*)d_in[5];
  const float* lamb   = (const float*)d_in[6];
  const float* W10    = (const float*)d_in[7];
  const float* W11    = (const float*)d_in[8];
  const float* b1     = (const float*)d_in[9];
  const float* W20    = (const float*)d_in[10];
  const float* W21    = (const float*)d_in[11];
  const float* b2     = (const float*)d_in[12];
  float* out = (float*)d_out;

  char* base = (char*)d_ws;
  size_t o = 0;
  auto alloc = [&](size_t bytes) { size_t r = o; o = (o + bytes + 255) & ~size_t(255); return r; };

  // zero-init region first (deg, cursor, xcg, t, s)
  size_t off_deg    = alloc(N_NODES * 4);
  size_t off_cursor = alloc(N_NODES * 4);
  size_t off_xcg    = alloc(NQ * 4);
  size_t off_t      = alloc(N_NODES * 4);
  size_t off_s      = alloc(N_NODES * 4);
  size_t zero_end   = o;
  size_t off_rowst  = alloc((N_NODES + 1) * 4);
  size_t off_dinv   = alloc(N_NODES * 4);
  size_t off_cols   = alloc(N_EDGES * 4);
  size_t off_wvals  = alloc(N_EDGES * 4);
  size_t off_msg1   = alloc((size_t)N_NODES * F_DIM * 4);
  size_t off_Abf    = alloc((size_t)M_ROWS * NQ * 2);
  size_t off_h2     = alloc(N_NODES * 4);
  size_t off_q      = alloc(NQ * 4);
  size_t off_r      = alloc(NQ * 4);
  size_t off_p0     = alloc(NQ * 4);
  size_t off_p1     = alloc(NQ * 4);
  size_t off_v      = alloc(M_ROWS * 4);
  size_t off_btAp   = alloc(32 * NQ * 4);
  size_t off_Qpp    = alloc(64 * NQ * 4);
  size_t off_pApp   = alloc(256 * 4);
  size_t off_rrp    = alloc((NIT + 1) * 8 * 4);
  if (o > ws_size) return;

  int*   deg      = (int*)(base + off_deg);
  int*   cursor   = (int*)(base + off_cursor);
  float* xcg      = (float*)(base + off_xcg);
  float* t        = (float*)(base + off_t);
  float* s        = (float*)(base + off_s);
  int*   rowstart = (int*)(base + off_rowst);
  float* dinv     = (float*)(base + off_dinv);
  int*   cols     = (int*)(base + off_cols);
  float* wvals    = (float*)(base + off_wvals);
  float* msg1     = (float*)(base + off_msg1);
  unsigned* Au    = (unsigned*)(base + off_Abf);
  float* h2       = (float*)(base + off_h2);
  float* q        = (float*)(base + off_q);
  float* rvec     = (float*)(base + off_r);
  float* pbuf[2]  = {(float*)(base + off_p0), (float*)(base + off_p1)};
  float* v        = (float*)(base + off_v);
  float* btA_parts = (float*)(base + off_btAp);
  float* Qp_parts  = (float*)(base + off_Qpp);
  float* pAp_parts = (float*)(base + off_pApp);
  float* rr_parts  = (float*)(base + off_rrp);

  hipMemsetAsync(d_ws, 0, zero_end, stream);

  // CSR build
  k_deg<<<(N_EDGES + 255) / 256, 256, 0, stream>>>(ei, deg);
  k_dinv<<<(N_NODES + 255) / 256, 256, 0, stream>>>(deg, dinv);
  k_scan<<<1, 1024, 0, stream>>>(deg, rowstart);
  k_scatter<<<(N_EDGES + 255) / 256, 256, 0, stream>>>(ei, rowstart, cursor, dinv, cols, wvals);

  // GNN
  k_msg1<<<N_NODES / 4, 256, 0, stream>>>(x, rowstart, cols, wvals, msg1);
  k_gemm1<<<dim3((N_NODES + 63) / 64, H_DIM / 64), 256, 0, stream>>>(
      x, msg1, W10, W11, b1, W20, W21, t, s);
  k_h2<<<(N_NODES + 255) / 256, 256, 0, stream>>>(t, s, rowstart, cols, wvals, lamb, b2, h2);

  // QP setup (bf16 A + b^T A), rhs + CG init
  k_prep<<<dim3(4, 32), 256, 0, stream>>>(A, b, Au, btA_parts);
  k_qrhs<<<NQ / 256, 256, 0, stream>>>(h2, fids, xprior, btA_parts, q, rvec, pbuf[0], rr_parts);

  // CG: 3 kernels/iter
  for (int k = 0; k < NIT; ++k) {
    float* p_cur = pbuf[k & 1];
    float* p_prev = pbuf[(k + 1) & 1];
    k_Ap<<<256, 256, 0, stream>>>(k, Au, rvec, p_prev, p_cur, rr_parts, v);
    k_ATv<<<dim3(4, 64), 256, 0, stream>>>(Au, v, p_cur, q, Qp_parts, pAp_parts);
    k_update<<<NQ / 256, 256, 0, stream>>>(k, Qp_parts, pAp_parts, rr_parts, q, p_cur, xcg, rvec, out);
  }
}